// Round 11
// baseline (142.382 us; speedup 1.0000x reference)
//
#include <hip/hip_runtime.h>
#include <math.h>

typedef __attribute__((ext_vector_type(8))) short s16x8;
typedef __attribute__((ext_vector_type(4))) float f32x4;
typedef __attribute__((ext_vector_type(4))) unsigned int u32x4;

#define CCH 128
#define BSZ 32

// fp32 -> bf16 round-to-nearest-even (scalar)
static __device__ inline unsigned short f2bf(float f) {
    unsigned u = __float_as_uint(f);
    unsigned r = (u + 0x7FFFu + ((u >> 16) & 1u)) >> 16;
    return (unsigned short)r;
}

// packed f32x2 -> bf16x2 (RNE)
static __device__ inline unsigned cvtpk(float lo, float hi) {
    unsigned r;
    asm("v_cvt_pk_bf16_f32 %0, %1, %2" : "=v"(r) : "v"(lo), "v"(hi));
    return r;
}

// ================= BIG-WS PATH =================
// xws layout per (b,cc): [66 rows][72 cols][4 oct][8 bf16] = 304128 B.
//  storage row rs = gy+1 (rs 0 and 65 are zero guard rows);
//  storage col cp = gx+1 (cp 0, 65..71 zero);
//  oct slot o' holds data oct o'^((cp>>1)&3)  (bank-conflict XOR, baked in).
// Conv then stages a 6-row window (27648 B, contiguous) with 27 global_load_lds
// whose only lane-varying address component is l*16 -> ~zero persistent VGPRs.

// ---------------- prep: fused GAP + x->bf16 padded/swizzled relayout ----------
// grid 512 = (b, cc, q): q = 16-row band. 256 threads.
__global__ __launch_bounds__(256, 2) void prep_kernel(const float* __restrict__ x,
                                                      unsigned short* __restrict__ xws,
                                                      float* __restrict__ pooled2) {
    int bid = blockIdx.x;
    int b = bid >> 4, cc = (bid >> 2) & 3, q = bid & 3;
    int t = threadIdx.x;
    const float* xb = x + ((size_t)b * CCH + cc * 32) * 4096;
    unsigned short* xo = xws + (size_t)(b * 4 + cc) * (66 * 72 * 32);

    float sums[32];
#pragma unroll
    for (int c = 0; c < 32; ++c) sums[c] = 0.f;

    // interior: 16 rows x 32 col-pairs = 512 tasks, 2 per thread
#pragma unroll
    for (int it = 0; it < 2; ++it) {
        int task = t + it * 256;
        int gy = q * 16 + (task >> 5);
        int i = task & 31;
        int gx0 = 2 * i;
        float2 v2[32];
#pragma unroll
        for (int c = 0; c < 32; ++c) {
            v2[c] = *(const float2*)&xb[(size_t)c * 4096 + gy * 64 + gx0];
            sums[c] += v2[c].x + v2[c].y;
        }
        int rs = gy + 1;
#pragma unroll
        for (int h = 0; h < 2; ++h) {
            int cp = gx0 + 1 + h;
            int xor3 = (cp >> 1) & 3;
            unsigned pw[16];
#pragma unroll
            for (int o = 0; o < 4; ++o) {
                int od = o ^ xor3;
#pragma unroll
                for (int j = 0; j < 4; ++j) {
                    float lo = h ? v2[od * 8 + 2 * j].y : v2[od * 8 + 2 * j].x;
                    float hi = h ? v2[od * 8 + 2 * j + 1].y : v2[od * 8 + 2 * j + 1].x;
                    pw[o * 4 + j] = cvtpk(lo, hi);
                }
            }
            unsigned short* dp = xo + ((size_t)rs * 72 + cp) * 32;
#pragma unroll
            for (int o = 0; o < 4; ++o) {
                u32x4 qv; qv[0] = pw[o*4+0]; qv[1] = pw[o*4+1]; qv[2] = pw[o*4+2]; qv[3] = pw[o*4+3];
                *(u32x4*)&dp[o * 8] = qv;
            }
        }
    }

    // zero slots: col halo for this band (128) + guard row (72) if q edge
    {
        int nz = 128 + ((q == 0 || q == 3) ? 72 : 0);
        if (t < nz) {
            int rs, cp;
            if (t < 128) {
                rs = q * 16 + 1 + (t >> 3);
                cp = ((t & 7) == 0) ? 0 : 64 + (t & 7);
            } else {
                rs = (q == 0) ? 0 : 65;
                cp = t - 128;
            }
            unsigned short* dp = xo + ((size_t)rs * 72 + cp) * 32;
            u32x4 zq = {0u, 0u, 0u, 0u};
#pragma unroll
            for (int o = 0; o < 4; ++o) *(u32x4*)&dp[o * 8] = zq;
        }
    }

    // block-reduce channel sums -> pooled2[((b*4+cc)*4+q)*32 + c] (pre-divided)
    __shared__ float red[4][32];
    int l = t & 63, wv = t >> 6;
#pragma unroll
    for (int c = 0; c < 32; ++c) {
        float s = sums[c];
        s += __shfl_xor(s, 1, 64); s += __shfl_xor(s, 2, 64); s += __shfl_xor(s, 4, 64);
        s += __shfl_xor(s, 8, 64); s += __shfl_xor(s, 16, 64); s += __shfl_xor(s, 32, 64);
        if (l == 0) red[wv][c] = s;
    }
    __syncthreads();
    if (t < 32) {
        float tot = red[0][t] + red[1][t] + red[2][t] + red[3][t];
        pooled2[((size_t)(b * 4 + cc) * 4 + q) * 32 + t] = tot * (1.0f / 4096.0f);
    }
}

// ---------------- coeff2: routing coefficients from band partials -------------
__global__ __launch_bounds__(128) void coeff2_kernel(const float* __restrict__ pooled2,
                                                     const float* __restrict__ fc_w,
                                                     const float* __restrict__ fc_b,
                                                     float* __restrict__ coeffs) {
    int t = threadIdx.x;
    int b = t >> 2, k = t & 3;
    float dot = fc_b[k];
#pragma unroll
    for (int cc = 0; cc < 4; ++cc) {
        const float4* p0 = (const float4*)(pooled2 + ((size_t)(b * 4 + cc) * 4 + 0) * 32);
        const float4* p1 = (const float4*)(pooled2 + ((size_t)(b * 4 + cc) * 4 + 1) * 32);
        const float4* p2 = (const float4*)(pooled2 + ((size_t)(b * 4 + cc) * 4 + 2) * 32);
        const float4* p3 = (const float4*)(pooled2 + ((size_t)(b * 4 + cc) * 4 + 3) * 32);
        const float4* w4 = (const float4*)(fc_w + k * CCH + cc * 32);
#pragma unroll
        for (int j = 0; j < 8; ++j) {
            float4 s4, w = w4[j];
            float4 a0 = p0[j], a1 = p1[j], a2 = p2[j], a3 = p3[j];
            s4.x = a0.x + a1.x + a2.x + a3.x; s4.y = a0.y + a1.y + a2.y + a3.y;
            s4.z = a0.z + a1.z + a2.z + a3.z; s4.w = a0.w + a1.w + a2.w + a3.w;
            dot += s4.x * w.x + s4.y * w.y + s4.z * w.z + s4.w * w.w;
        }
    }
    float s = 1.0f / (1.0f + expf(-dot));
    float m = s;
    m = fmaxf(m, __shfl_xor(m, 1, 64));
    m = fmaxf(m, __shfl_xor(m, 2, 64));
    float e = expf(s - m);
    float sum = e;
    sum += __shfl_xor(sum, 1, 64);
    sum += __shfl_xor(sum, 2, 64);
    coeffs[t] = e / sum;
}

// ---------------- Kernel W: mix -> bf16 in conv tile layout (both paths) ------
// wmix per b: [p(12)][dx(3)][wr(2)][mt(4)][lane(64)][8 bf16]  (1024 B tiles)
__global__ __launch_bounds__(256) void mix_kernel(const float* __restrict__ kernels,
                                                  const float* __restrict__ coeffs,
                                                  unsigned short* __restrict__ wmix) {
    extern __shared__ float klds[];   // 4*4624 = 18496 floats (73984 B)
    int bid = blockIdx.x;
    int bq = bid & 15;
    int rest = bid >> 4;              // 0..31
    int cog = rest & 7, cc = rest >> 3;
    int t = threadIdx.x;

    const int KSTR = CCH * CCH * 9;
    for (int s = t; s < 4 * 16 * 288; s += 256) {
        int k = s / 4608;
        int rem = s - k * 4608;
        int co = rem / 288;
        int i = rem - co * 288;            // ci*9 + tap
        klds[k * 4624 + co * 289 + i] =
            kernels[(size_t)k * KSTR + ((size_t)(cog * 16 + co) * CCH + cc * 32) * 9 + i];
    }
    __syncthreads();

    int wr = cog >> 2, mt = cog & 3;
#pragma unroll
    for (int jb = 0; jb < 2; ++jb) {
        int b = bq + jb * 16;
        float cf0 = coeffs[b * 4 + 0];
        float cf1 = coeffs[b * 4 + 1];
        float cf2 = coeffs[b * 4 + 2];
        float cf3 = coeffs[b * 4 + 3];
        for (int s = t; s < 576; s += 256) {
            int lane = s & 63;
            int tj = s >> 6;                 // 0..8
            int dy = tj / 3, dx = tj - dy * 3;
            int col = lane & 15;             // co_local
            int ci8 = (lane >> 4) * 8;
            unsigned short vals[8];
#pragma unroll
            for (int e = 0; e < 8; ++e) {
                int idx = col * 289 + (ci8 + e) * 9 + dy * 3 + dx;
                float v = cf0 * klds[idx]
                        + cf1 * klds[4624 + idx]
                        + cf2 * klds[2 * 4624 + idx]
                        + cf3 * klds[3 * 4624 + idx];
                vals[e] = f2bf(v);
            }
            int p = cc * 3 + dy;
            size_t off = (size_t)b * 147456
                       + ((size_t)((p * 3 + dx) * 2 + wr) * 4 + mt) * 512 + (size_t)lane * 8;
            *(s16x8*)&wmix[off] = *(const s16x8*)vals;
        }
    }
}

// ---------------- conv (big path): zero-VGPR staging via global_load_lds ------
// grid = 512 (32 b x 16 ytiles of 4 rows), 512 threads (8 waves: wr2 x wc4).
// xs double-buffered 2x27648 B; 27 contiguous 1024B DMA loads/phase, source =
// SGPR window base + s*1024 + l*16. Staging for cc+1 issued mid-phase (tap 5).
__global__ __launch_bounds__(512, 4) void conv_kernel(const unsigned short* __restrict__ xws,
                                                      const unsigned short* __restrict__ wmix,
                                                      float* __restrict__ out) {
    __shared__ unsigned short xs[2][13824];   // 2 x 27648 B

    int bid = blockIdx.x;
    int b = bid & 31, ytile = bid >> 5;
    int y0 = ytile * 4;
    int t = threadIdx.x;
    int l = t & 63, w = t >> 6;
    int wr = w >> 2, wc = w & 3;
    int l15 = l & 15, g = l >> 4;
    int lane16 = l * 16;

    const unsigned short* wb = wmix + (size_t)b * 147456;
    const char* xwsB = (const char*)xws;
    // window byte base for chunk cc: rows y0..y0+5 of (b,cc) block
    size_t win0 = ((size_t)(b * 4) * 66 + y0) * 4608;
    const size_t CCSTRIDE = (size_t)66 * 4608;   // 304128 B per cc

#define STAGE_X(ccn, buf)                                                        \
    do {                                                                         \
        const char* srcb = xwsB + win0 + (size_t)(ccn) * CCSTRIDE;               \
        unsigned short* dstb = &xs[buf][0];                                      \
        _Pragma("unroll")                                                        \
        for (int k = 0; k < 4; ++k) {                                            \
            int s = w + k * 8;                                                   \
            if (s < 27) {                                                        \
                __builtin_amdgcn_global_load_lds(                                \
                    (const __attribute__((address_space(1))) void*)(srcb + s * 1024 + lane16), \
                    (__attribute__((address_space(3))) void*)(dstb + s * 512),   \
                    16, 0, 0);                                                   \
            }                                                                    \
        }                                                                        \
    } while (0)

    // ---- prologue: stage cc=0 into buf 0 ----
    STAGE_X(0, 0);
    __syncthreads();

    f32x4 acc[4][4] = {};

    for (int cc = 0; cc < 4; ++cc) {
        const unsigned short* xcur = &xs[cc & 1][0];
#pragma unroll
        for (int tap = 0; tap < 9; ++tap) {
            // mid-phase staging issue: preceding taps' A-retires are unaffected,
            // remaining 4 taps of MFMA cover the DMA latency before the barrier.
            if (tap == 5 && cc < 3) STAGE_X(cc + 1, (cc + 1) & 1);
            int dy = tap / 3, dx = tap - dy * 3;
            int p = cc * 3 + dy;
            int rl = wc + dy;
            const unsigned short* wt = wb + ((size_t)((p * 3 + dx) * 2 + wr) * 4) * 512
                                          + (size_t)l * 8;
            s16x8 a[4];
#pragma unroll
            for (int mt = 0; mt < 4; ++mt)
                a[mt] = *(const s16x8*)(wt + mt * 512);
#pragma unroll
            for (int nt = 0; nt < 4; ++nt) {
                int cp = nt * 16 + l15 + dx;        // storage col 0..65
                s16x8 bf = *(const s16x8*)&xcur[((size_t)rl * 72 + cp) * 32
                                                + (g ^ ((cp >> 1) & 3)) * 8];
#pragma unroll
                for (int mt = 0; mt < 4; ++mt)
                    acc[mt][nt] = __builtin_amdgcn_mfma_f32_16x16x32_bf16(
                        a[mt], bf, acc[mt][nt], 0, 0, 0);
            }
        }
        __syncthreads();   // drains vmcnt: next buffer staged; current reads quiesced
    }
#undef STAGE_X

    // ---- epilogue ----
    int gy = y0 + wc;
#pragma unroll
    for (int mt = 0; mt < 4; ++mt)
#pragma unroll
        for (int nt = 0; nt < 4; ++nt) {
            int gxo = nt * 16 + l15;
#pragma unroll
            for (int j = 0; j < 4; ++j) {
                int co = wr * 64 + mt * 16 + g * 4 + j;
                out[(((size_t)b * CCH + co) * 64 + gy) * 64 + gxo] = acc[mt][nt][j];
            }
        }
}

// ================= FALLBACK PATH (round-6, proven) =================

__global__ __launch_bounds__(256) void pool_kernel(const float* __restrict__ x,
                                                   float* __restrict__ pooled) {
    int blk = blockIdx.x;
    const float4* x4 = (const float4*)(x + (size_t)blk * 4096);
    int t = threadIdx.x;
    float s = 0.f;
#pragma unroll
    for (int j = 0; j < 4; ++j) {
        float4 v = x4[j * 256 + t];
        s += v.x + v.y + v.z + v.w;
    }
#pragma unroll
    for (int off = 32; off; off >>= 1) s += __shfl_xor(s, off, 64);
    __shared__ float red[4];
    if ((t & 63) == 0) red[t >> 6] = s;
    __syncthreads();
    if (t == 0) {
        float tot = red[0] + red[1] + red[2] + red[3];
        pooled[blk] = tot * (1.0f / 4096.0f);
    }
}

__global__ __launch_bounds__(128) void coeff_kernel(const float* __restrict__ pooled,
                                                    const float* __restrict__ fc_w,
                                                    const float* __restrict__ fc_b,
                                                    float* __restrict__ coeffs) {
    int t = threadIdx.x;
    int b = t >> 2, k = t & 3;
    const float4* p4 = (const float4*)(pooled + b * CCH);
    const float4* w4 = (const float4*)(fc_w + k * CCH);
    float dot = fc_b[k];
#pragma unroll
    for (int j = 0; j < 32; ++j) {
        float4 a = p4[j], w = w4[j];
        dot += a.x * w.x + a.y * w.y + a.z * w.z + a.w * w.w;
    }
    float s = 1.0f / (1.0f + expf(-dot));
    float m = s;
    m = fmaxf(m, __shfl_xor(m, 1, 64));
    m = fmaxf(m, __shfl_xor(m, 2, 64));
    float e = expf(s - m);
    float sum = e;
    sum += __shfl_xor(sum, 1, 64);
    sum += __shfl_xor(sum, 2, 64);
    coeffs[t] = e / sum;
}

__global__ __launch_bounds__(512, 4) void conv_fb_kernel(const float* __restrict__ x,
                                                         const unsigned short* __restrict__ wmix,
                                                         float* __restrict__ out) {
    __shared__ unsigned short xsb[6 * 66 * 40];

    int bid = blockIdx.x;
    int b = bid & 31, ytile = bid >> 5;
    int y0 = ytile * 4;
    int t = threadIdx.x;
    int l = t & 63, w = t >> 6;
    int wr = w >> 2, wc = w & 3;
    int l15 = l & 15, g = l >> 4;

    const unsigned short* wb = wmix + (size_t)b * 147456;

    if (t < 240) {
        int row = t / 40;
        int colsel = (t / 20) & 1;
        int cpart = t % 20;
        *(unsigned*)&xsb[(row * 66 + colsel * 65) * 40 + cpart * 2] = 0u;
    }

    f32x4 acc[4][4] = {};

    for (int cc = 0; cc < 4; ++cc) {
        __syncthreads();
#pragma unroll
        for (int i = 0; i < 3; ++i) {
            int slot = w + i * 8;
            int row = slot >> 2, colhi = slot & 3;
            int gx = colhi * 16 + l15;
            int gy = y0 + row - 1;
            float v[8];
#pragma unroll
            for (int j = 0; j < 8; ++j) v[j] = 0.f;
            if ((unsigned)gy < 64u) {
                const float* xp = x + (((size_t)b * CCH + cc * 32 + g * 8) * 64 + gy) * 64 + gx;
#pragma unroll
                for (int j = 0; j < 8; ++j) v[j] = xp[(size_t)j * 4096];
            }
            unsigned pk[4];
#pragma unroll
            for (int j = 0; j < 4; ++j)
                pk[j] = (unsigned)f2bf(v[2 * j]) | ((unsigned)f2bf(v[2 * j + 1]) << 16);
            u32x4 qv; qv[0] = pk[0]; qv[1] = pk[1]; qv[2] = pk[2]; qv[3] = pk[3];
            *(u32x4*)&xsb[(size_t)(row * 66 + gx + 1) * 40 + g * 8] = qv;
        }
        __syncthreads();
#pragma unroll
        for (int dy = 0; dy < 3; ++dy) {
            int p = cc * 3 + dy;
            int xrow = wc + dy;
#pragma unroll
            for (int dx = 0; dx < 3; ++dx) {
                const unsigned short* wt = wb + ((size_t)((p * 3 + dx) * 2 + wr) * 4) * 512
                                              + (size_t)l * 8;
                s16x8 a[4];
#pragma unroll
                for (int mt = 0; mt < 4; ++mt)
                    a[mt] = *(const s16x8*)(wt + mt * 512);
#pragma unroll
                for (int nt = 0; nt < 4; ++nt) {
                    s16x8 bf = *(const s16x8*)&xsb[(size_t)(xrow * 66 + nt * 16 + l15 + dx) * 40 + g * 8];
#pragma unroll
                    for (int mt = 0; mt < 4; ++mt)
                        acc[mt][nt] = __builtin_amdgcn_mfma_f32_16x16x32_bf16(
                            a[mt], bf, acc[mt][nt], 0, 0, 0);
                }
            }
        }
    }

    int gy = y0 + wc;
#pragma unroll
    for (int mt = 0; mt < 4; ++mt)
#pragma unroll
        for (int nt = 0; nt < 4; ++nt) {
            int gxo = nt * 16 + l15;
#pragma unroll
            for (int j = 0; j < 4; ++j) {
                int co = wr * 64 + mt * 16 + g * 4 + j;
                out[(((size_t)b * CCH + co) * 64 + gy) * 64 + gxo] = acc[mt][nt][j];
            }
        }
}

extern "C" void kernel_launch(void* const* d_in, const int* in_sizes, int n_in,
                              void* d_out, int out_size, void* d_ws, size_t ws_size,
                              hipStream_t stream) {
    const float* x       = (const float*)d_in[0];   // [32,128,64,64]
    const float* kernels = (const float*)d_in[1];   // [4,128,128,3,3]
    const float* fc_w    = (const float*)d_in[2];   // [4,128]
    const float* fc_b    = (const float*)d_in[3];   // [4]
    float* out = (float*)d_out;

    hipFuncSetAttribute((const void*)mix_kernel,
                        hipFuncAttributeMaxDynamicSharedMemorySize, 73984);

    // pooled2 64KB @0 | coeffs @65536 | wmix @73728 (9.44MB) | xws @9510912 (38.93MB)
    const size_t NEED = 9510912ull + 38928384ull;   // 48.44 MB
    if (ws_size >= NEED) {
        float* pooled2        = (float*)d_ws;
        float* coeffs         = (float*)((char*)d_ws + 65536);
        unsigned short* wmix  = (unsigned short*)((char*)d_ws + 73728);
        unsigned short* xws   = (unsigned short*)((char*)d_ws + 9510912);

        prep_kernel<<<512, 256, 0, stream>>>(x, xws, pooled2);
        coeff2_kernel<<<1, 128, 0, stream>>>(pooled2, fc_w, fc_b, coeffs);
        mix_kernel<<<512, 256, 73984, stream>>>(kernels, coeffs, wmix);
        conv_kernel<<<512, 512, 0, stream>>>(xws, wmix, out);
    } else {
        float* pooled = (float*)d_ws;
        float* coeffs = pooled + BSZ * CCH;
        unsigned short* wmix = (unsigned short*)((char*)d_ws + 32768);

        pool_kernel<<<BSZ * CCH, 256, 0, stream>>>(x, pooled);
        coeff_kernel<<<1, 128, 0, stream>>>(pooled, fc_w, fc_b, coeffs);
        mix_kernel<<<512, 256, 73984, stream>>>(kernels, coeffs, wmix);
        conv_fb_kernel<<<512, 512, 0, stream>>>(x, wmix, out);
    }
}

// Round 12
// 115.830 us; speedup vs baseline: 1.2292x; 1.2292x over previous
//
#include <hip/hip_runtime.h>
#include <math.h>

typedef __attribute__((ext_vector_type(8))) short s16x8;
typedef __attribute__((ext_vector_type(4))) float f32x4;
typedef __attribute__((ext_vector_type(4))) unsigned int u32x4;

#define CCH 128
#define BSZ 32

// fp32 -> bf16 round-to-nearest-even (scalar)
static __device__ inline unsigned short f2bf(float f) {
    unsigned u = __float_as_uint(f);
    unsigned r = (u + 0x7FFFu + ((u >> 16) & 1u)) >> 16;
    return (unsigned short)r;
}

// packed f32x2 -> bf16x2 (RNE)
static __device__ inline unsigned cvtpk(float lo, float hi) {
    unsigned r;
    asm("v_cvt_pk_bf16_f32 %0, %1, %2" : "=v"(r) : "v"(lo), "v"(hi));
    return r;
}

// ================= BIG-WS PATH =================
// xws layout per (b,cc): [66 rows][72 cols][4 oct][8 bf16] = 304128 B.
//  storage row rs = gy+1 (rs 0 and 65 are zero guard rows);
//  storage col cp = gx+1 (cp 0, 65..71 zero);
//  oct slot o' holds data oct o'^((cp>>1)&3)  (bank-conflict XOR, baked in).

// ---------------- prep: fused GAP + x->bf16 padded/swizzled relayout ----------
// grid 512 = (b, cc, q): q = 16-row band. 256 threads.
// NOTE: data-oct loop is STATIC; the XOR swizzle is applied to the STORE
// ADDRESS (slot = od ^ xor3), never to a register-array index (rule #20:
// runtime-indexed ext_vector arrays spill to scratch -- round-11 bug).
__global__ __launch_bounds__(256, 2) void prep_kernel(const float* __restrict__ x,
                                                      unsigned short* __restrict__ xws,
                                                      float* __restrict__ pooled2) {
    int bid = blockIdx.x;
    int b = bid >> 4, cc = (bid >> 2) & 3, q = bid & 3;
    int t = threadIdx.x;
    const float* xb = x + ((size_t)b * CCH + cc * 32) * 4096;
    unsigned short* xo = xws + (size_t)(b * 4 + cc) * (66 * 72 * 32);

    float sums[32];
#pragma unroll
    for (int c = 0; c < 32; ++c) sums[c] = 0.f;

    // interior: 16 rows x 32 col-pairs = 512 tasks, 2 per thread
#pragma unroll
    for (int it = 0; it < 2; ++it) {
        int task = t + it * 256;
        int gy = q * 16 + (task >> 5);
        int i = task & 31;
        int gx0 = 2 * i;
        float2 v2[32];
#pragma unroll
        for (int c = 0; c < 32; ++c) {
            v2[c] = *(const float2*)&xb[(size_t)c * 4096 + gy * 64 + gx0];
            sums[c] += v2[c].x + v2[c].y;
        }
        int rs = gy + 1;
        int cp0 = gx0 + 1, cp1 = gx0 + 2;
        int xor0 = (cp0 >> 1) & 3, xor1 = (cp1 >> 1) & 3;
        unsigned short* dp0 = xo + ((size_t)rs * 72 + cp0) * 32;
        unsigned short* dp1 = xo + ((size_t)rs * 72 + cp1) * 32;
#pragma unroll
        for (int od = 0; od < 4; ++od) {      // data oct, STATIC index into v2
            u32x4 q0, q1;
#pragma unroll
            for (int j = 0; j < 4; ++j) {
                float2 a = v2[od * 8 + 2 * j];
                float2 c2 = v2[od * 8 + 2 * j + 1];
                q0[j] = cvtpk(a.x, c2.x);     // h=0 (col cp0)
                q1[j] = cvtpk(a.y, c2.y);     // h=1 (col cp1)
            }
            *(u32x4*)&dp0[(od ^ xor0) * 8] = q0;
            *(u32x4*)&dp1[(od ^ xor1) * 8] = q1;
        }
    }

    // zero slots: col halo for this band (128) + guard row (72) if q edge
    {
        int nz = 128 + ((q == 0 || q == 3) ? 72 : 0);
        if (t < nz) {
            int rs, cp;
            if (t < 128) {
                rs = q * 16 + 1 + (t >> 3);
                cp = ((t & 7) == 0) ? 0 : 64 + (t & 7);
            } else {
                rs = (q == 0) ? 0 : 65;
                cp = t - 128;
            }
            unsigned short* dp = xo + ((size_t)rs * 72 + cp) * 32;
            u32x4 zq = {0u, 0u, 0u, 0u};
#pragma unroll
            for (int o = 0; o < 4; ++o) *(u32x4*)&dp[o * 8] = zq;
        }
    }

    // block-reduce channel sums -> pooled2[((b*4+cc)*4+q)*32 + c] (pre-divided)
    __shared__ float red[4][32];
    int l = t & 63, wv = t >> 6;
#pragma unroll
    for (int c = 0; c < 32; ++c) {
        float s = sums[c];
        s += __shfl_xor(s, 1, 64); s += __shfl_xor(s, 2, 64); s += __shfl_xor(s, 4, 64);
        s += __shfl_xor(s, 8, 64); s += __shfl_xor(s, 16, 64); s += __shfl_xor(s, 32, 64);
        if (l == 0) red[wv][c] = s;
    }
    __syncthreads();
    if (t < 32) {
        float tot = red[0][t] + red[1][t] + red[2][t] + red[3][t];
        pooled2[((size_t)(b * 4 + cc) * 4 + q) * 32 + t] = tot * (1.0f / 4096.0f);
    }
}

// ---------------- coeff2: routing coefficients from band partials -------------
__global__ __launch_bounds__(128) void coeff2_kernel(const float* __restrict__ pooled2,
                                                     const float* __restrict__ fc_w,
                                                     const float* __restrict__ fc_b,
                                                     float* __restrict__ coeffs) {
    int t = threadIdx.x;
    int b = t >> 2, k = t & 3;
    float dot = fc_b[k];
#pragma unroll
    for (int cc = 0; cc < 4; ++cc) {
        const float4* p0 = (const float4*)(pooled2 + ((size_t)(b * 4 + cc) * 4 + 0) * 32);
        const float4* p1 = (const float4*)(pooled2 + ((size_t)(b * 4 + cc) * 4 + 1) * 32);
        const float4* p2 = (const float4*)(pooled2 + ((size_t)(b * 4 + cc) * 4 + 2) * 32);
        const float4* p3 = (const float4*)(pooled2 + ((size_t)(b * 4 + cc) * 4 + 3) * 32);
        const float4* w4 = (const float4*)(fc_w + k * CCH + cc * 32);
#pragma unroll
        for (int j = 0; j < 8; ++j) {
            float4 s4, w = w4[j];
            float4 a0 = p0[j], a1 = p1[j], a2 = p2[j], a3 = p3[j];
            s4.x = a0.x + a1.x + a2.x + a3.x; s4.y = a0.y + a1.y + a2.y + a3.y;
            s4.z = a0.z + a1.z + a2.z + a3.z; s4.w = a0.w + a1.w + a2.w + a3.w;
            dot += s4.x * w.x + s4.y * w.y + s4.z * w.z + s4.w * w.w;
        }
    }
    float s = 1.0f / (1.0f + expf(-dot));
    float m = s;
    m = fmaxf(m, __shfl_xor(m, 1, 64));
    m = fmaxf(m, __shfl_xor(m, 2, 64));
    float e = expf(s - m);
    float sum = e;
    sum += __shfl_xor(sum, 1, 64);
    sum += __shfl_xor(sum, 2, 64);
    coeffs[t] = e / sum;
}

// ---------------- Kernel W: mix -> bf16 in conv tile layout (both paths) ------
// wmix per b: [p(12)][dx(3)][wr(2)][mt(4)][lane(64)][8 bf16]  (1024 B tiles)
__global__ __launch_bounds__(256) void mix_kernel(const float* __restrict__ kernels,
                                                  const float* __restrict__ coeffs,
                                                  unsigned short* __restrict__ wmix) {
    extern __shared__ float klds[];   // 4*4624 = 18496 floats (73984 B)
    int bid = blockIdx.x;
    int bq = bid & 15;
    int rest = bid >> 4;              // 0..31
    int cog = rest & 7, cc = rest >> 3;
    int t = threadIdx.x;

    const int KSTR = CCH * CCH * 9;
    for (int s = t; s < 4 * 16 * 288; s += 256) {
        int k = s / 4608;
        int rem = s - k * 4608;
        int co = rem / 288;
        int i = rem - co * 288;            // ci*9 + tap
        klds[k * 4624 + co * 289 + i] =
            kernels[(size_t)k * KSTR + ((size_t)(cog * 16 + co) * CCH + cc * 32) * 9 + i];
    }
    __syncthreads();

    int wr = cog >> 2, mt = cog & 3;
#pragma unroll
    for (int jb = 0; jb < 2; ++jb) {
        int b = bq + jb * 16;
        float cf0 = coeffs[b * 4 + 0];
        float cf1 = coeffs[b * 4 + 1];
        float cf2 = coeffs[b * 4 + 2];
        float cf3 = coeffs[b * 4 + 3];
        for (int s = t; s < 576; s += 256) {
            int lane = s & 63;
            int tj = s >> 6;                 // 0..8
            int dy = tj / 3, dx = tj - dy * 3;
            int col = lane & 15;             // co_local
            int ci8 = (lane >> 4) * 8;
            unsigned short vals[8];
#pragma unroll
            for (int e = 0; e < 8; ++e) {
                int idx = col * 289 + (ci8 + e) * 9 + dy * 3 + dx;
                float v = cf0 * klds[idx]
                        + cf1 * klds[4624 + idx]
                        + cf2 * klds[2 * 4624 + idx]
                        + cf3 * klds[3 * 4624 + idx];
                vals[e] = f2bf(v);
            }
            int p = cc * 3 + dy;
            size_t off = (size_t)b * 147456
                       + ((size_t)((p * 3 + dx) * 2 + wr) * 4 + mt) * 512 + (size_t)lane * 8;
            *(s16x8*)&wmix[off] = *(const s16x8*)vals;
        }
    }
}

// ---------------- conv (big path): zero-VGPR staging via global_load_lds ------
// grid = 512 (32 b x 16 ytiles of 4 rows), 512 threads (8 waves: wr2 x wc4).
// xs double-buffered 2x27648 B; 27 contiguous 1024B DMA loads/phase, source =
// SGPR window base + s*1024 + l*16. Staging for cc+1 issued mid-phase (tap 5).
__global__ __launch_bounds__(512, 4) void conv_kernel(const unsigned short* __restrict__ xws,
                                                      const unsigned short* __restrict__ wmix,
                                                      float* __restrict__ out) {
    __shared__ unsigned short xs[2][13824];   // 2 x 27648 B

    int bid = blockIdx.x;
    int b = bid & 31, ytile = bid >> 5;
    int y0 = ytile * 4;
    int t = threadIdx.x;
    int l = t & 63, w = t >> 6;
    int wr = w >> 2, wc = w & 3;
    int l15 = l & 15, g = l >> 4;
    int lane16 = l * 16;

    const unsigned short* wb = wmix + (size_t)b * 147456;
    const char* xwsB = (const char*)xws;
    size_t win0 = ((size_t)(b * 4) * 66 + y0) * 4608;
    const size_t CCSTRIDE = (size_t)66 * 4608;   // 304128 B per cc

#define STAGE_X(ccn, buf)                                                        \
    do {                                                                         \
        const char* srcb = xwsB + win0 + (size_t)(ccn) * CCSTRIDE;               \
        unsigned short* dstb = &xs[buf][0];                                      \
        _Pragma("unroll")                                                        \
        for (int k = 0; k < 4; ++k) {                                            \
            int s = w + k * 8;                                                   \
            if (s < 27) {                                                        \
                __builtin_amdgcn_global_load_lds(                                \
                    (const __attribute__((address_space(1))) void*)(srcb + s * 1024 + lane16), \
                    (__attribute__((address_space(3))) void*)(dstb + s * 512),   \
                    16, 0, 0);                                                   \
            }                                                                    \
        }                                                                        \
    } while (0)

    // ---- prologue: stage cc=0 into buf 0 ----
    STAGE_X(0, 0);
    __syncthreads();

    f32x4 acc[4][4] = {};

    for (int cc = 0; cc < 4; ++cc) {
        const unsigned short* xcur = &xs[cc & 1][0];
#pragma unroll
        for (int tap = 0; tap < 9; ++tap) {
            if (tap == 5 && cc < 3) STAGE_X(cc + 1, (cc + 1) & 1);
            int dy = tap / 3, dx = tap - dy * 3;
            int p = cc * 3 + dy;
            int rl = wc + dy;
            const unsigned short* wt = wb + ((size_t)((p * 3 + dx) * 2 + wr) * 4) * 512
                                          + (size_t)l * 8;
            s16x8 a[4];
#pragma unroll
            for (int mt = 0; mt < 4; ++mt)
                a[mt] = *(const s16x8*)(wt + mt * 512);
#pragma unroll
            for (int nt = 0; nt < 4; ++nt) {
                int cp = nt * 16 + l15 + dx;        // storage col 0..65
                s16x8 bf = *(const s16x8*)&xcur[((size_t)rl * 72 + cp) * 32
                                                + (g ^ ((cp >> 1) & 3)) * 8];
#pragma unroll
                for (int mt = 0; mt < 4; ++mt)
                    acc[mt][nt] = __builtin_amdgcn_mfma_f32_16x16x32_bf16(
                        a[mt], bf, acc[mt][nt], 0, 0, 0);
            }
        }
        __syncthreads();   // drains vmcnt: next buffer staged; current reads quiesced
    }
#undef STAGE_X

    // ---- epilogue ----
    int gy = y0 + wc;
#pragma unroll
    for (int mt = 0; mt < 4; ++mt)
#pragma unroll
        for (int nt = 0; nt < 4; ++nt) {
            int gxo = nt * 16 + l15;
#pragma unroll
            for (int j = 0; j < 4; ++j) {
                int co = wr * 64 + mt * 16 + g * 4 + j;
                out[(((size_t)b * CCH + co) * 64 + gy) * 64 + gxo] = acc[mt][nt][j];
            }
        }
}

// ================= FALLBACK PATH (round-6, proven) =================

__global__ __launch_bounds__(256) void pool_kernel(const float* __restrict__ x,
                                                   float* __restrict__ pooled) {
    int blk = blockIdx.x;
    const float4* x4 = (const float4*)(x + (size_t)blk * 4096);
    int t = threadIdx.x;
    float s = 0.f;
#pragma unroll
    for (int j = 0; j < 4; ++j) {
        float4 v = x4[j * 256 + t];
        s += v.x + v.y + v.z + v.w;
    }
#pragma unroll
    for (int off = 32; off; off >>= 1) s += __shfl_xor(s, off, 64);
    __shared__ float red[4];
    if ((t & 63) == 0) red[t >> 6] = s;
    __syncthreads();
    if (t == 0) {
        float tot = red[0] + red[1] + red[2] + red[3];
        pooled[blk] = tot * (1.0f / 4096.0f);
    }
}

__global__ __launch_bounds__(128) void coeff_kernel(const float* __restrict__ pooled,
                                                    const float* __restrict__ fc_w,
                                                    const float* __restrict__ fc_b,
                                                    float* __restrict__ coeffs) {
    int t = threadIdx.x;
    int b = t >> 2, k = t & 3;
    const float4* p4 = (const float4*)(pooled + b * CCH);
    const float4* w4 = (const float4*)(fc_w + k * CCH);
    float dot = fc_b[k];
#pragma unroll
    for (int j = 0; j < 32; ++j) {
        float4 a = p4[j], w = w4[j];
        dot += a.x * w.x + a.y * w.y + a.z * w.z + a.w * w.w;
    }
    float s = 1.0f / (1.0f + expf(-dot));
    float m = s;
    m = fmaxf(m, __shfl_xor(m, 1, 64));
    m = fmaxf(m, __shfl_xor(m, 2, 64));
    float e = expf(s - m);
    float sum = e;
    sum += __shfl_xor(sum, 1, 64);
    sum += __shfl_xor(sum, 2, 64);
    coeffs[t] = e / sum;
}

__global__ __launch_bounds__(512, 4) void conv_fb_kernel(const float* __restrict__ x,
                                                         const unsigned short* __restrict__ wmix,
                                                         float* __restrict__ out) {
    __shared__ unsigned short xsb[6 * 66 * 40];

    int bid = blockIdx.x;
    int b = bid & 31, ytile = bid >> 5;
    int y0 = ytile * 4;
    int t = threadIdx.x;
    int l = t & 63, w = t >> 6;
    int wr = w >> 2, wc = w & 3;
    int l15 = l & 15, g = l >> 4;

    const unsigned short* wb = wmix + (size_t)b * 147456;

    if (t < 240) {
        int row = t / 40;
        int colsel = (t / 20) & 1;
        int cpart = t % 20;
        *(unsigned*)&xsb[(row * 66 + colsel * 65) * 40 + cpart * 2] = 0u;
    }

    f32x4 acc[4][4] = {};

    for (int cc = 0; cc < 4; ++cc) {
        __syncthreads();
#pragma unroll
        for (int i = 0; i < 3; ++i) {
            int slot = w + i * 8;
            int row = slot >> 2, colhi = slot & 3;
            int gx = colhi * 16 + l15;
            int gy = y0 + row - 1;
            float v[8];
#pragma unroll
            for (int j = 0; j < 8; ++j) v[j] = 0.f;
            if ((unsigned)gy < 64u) {
                const float* xp = x + (((size_t)b * CCH + cc * 32 + g * 8) * 64 + gy) * 64 + gx;
#pragma unroll
                for (int j = 0; j < 8; ++j) v[j] = xp[(size_t)j * 4096];
            }
            unsigned pk[4];
#pragma unroll
            for (int j = 0; j < 4; ++j)
                pk[j] = (unsigned)f2bf(v[2 * j]) | ((unsigned)f2bf(v[2 * j + 1]) << 16);
            u32x4 qv; qv[0] = pk[0]; qv[1] = pk[1]; qv[2] = pk[2]; qv[3] = pk[3];
            *(u32x4*)&xsb[(size_t)(row * 66 + gx + 1) * 40 + g * 8] = qv;
        }
        __syncthreads();
#pragma unroll
        for (int dy = 0; dy < 3; ++dy) {
            int p = cc * 3 + dy;
            int xrow = wc + dy;
#pragma unroll
            for (int dx = 0; dx < 3; ++dx) {
                const unsigned short* wt = wb + ((size_t)((p * 3 + dx) * 2 + wr) * 4) * 512
                                              + (size_t)l * 8;
                s16x8 a[4];
#pragma unroll
                for (int mt = 0; mt < 4; ++mt)
                    a[mt] = *(const s16x8*)(wt + mt * 512);
#pragma unroll
                for (int nt = 0; nt < 4; ++nt) {
                    s16x8 bf = *(const s16x8*)&xsb[(size_t)(xrow * 66 + nt * 16 + l15 + dx) * 40 + g * 8];
#pragma unroll
                    for (int mt = 0; mt < 4; ++mt)
                        acc[mt][nt] = __builtin_amdgcn_mfma_f32_16x16x32_bf16(
                            a[mt], bf, acc[mt][nt], 0, 0, 0);
                }
            }
        }
    }

    int gy = y0 + wc;
#pragma unroll
    for (int mt = 0; mt < 4; ++mt)
#pragma unroll
        for (int nt = 0; nt < 4; ++nt) {
            int gxo = nt * 16 + l15;
#pragma unroll
            for (int j = 0; j < 4; ++j) {
                int co = wr * 64 + mt * 16 + g * 4 + j;
                out[(((size_t)b * CCH + co) * 64 + gy) * 64 + gxo] = acc[mt][nt][j];
            }
        }
}

extern "C" void kernel_launch(void* const* d_in, const int* in_sizes, int n_in,
                              void* d_out, int out_size, void* d_ws, size_t ws_size,
                              hipStream_t stream) {
    const float* x       = (const float*)d_in[0];   // [32,128,64,64]
    const float* kernels = (const float*)d_in[1];   // [4,128,128,3,3]
    const float* fc_w    = (const float*)d_in[2];   // [4,128]
    const float* fc_b    = (const float*)d_in[3];   // [4]
    float* out = (float*)d_out;

    hipFuncSetAttribute((const void*)mix_kernel,
                        hipFuncAttributeMaxDynamicSharedMemorySize, 73984);

    // pooled2 64KB @0 | coeffs @65536 | wmix @73728 (9.44MB) | xws @9510912 (38.93MB)
    const size_t NEED = 9510912ull + 38928384ull;   // 48.44 MB
    if (ws_size >= NEED) {
        float* pooled2        = (float*)d_ws;
        float* coeffs         = (float*)((char*)d_ws + 65536);
        unsigned short* wmix  = (unsigned short*)((char*)d_ws + 73728);
        unsigned short* xws   = (unsigned short*)((char*)d_ws + 9510912);

        prep_kernel<<<512, 256, 0, stream>>>(x, xws, pooled2);
        coeff2_kernel<<<1, 128, 0, stream>>>(pooled2, fc_w, fc_b, coeffs);
        mix_kernel<<<512, 256, 73984, stream>>>(kernels, coeffs, wmix);
        conv_kernel<<<512, 512, 0, stream>>>(xws, wmix, out);
    } else {
        float* pooled = (float*)d_ws;
        float* coeffs = pooled + BSZ * CCH;
        unsigned short* wmix = (unsigned short*)((char*)d_ws + 32768);

        pool_kernel<<<BSZ * CCH, 256, 0, stream>>>(x, pooled);
        coeff_kernel<<<1, 128, 0, stream>>>(pooled, fc_w, fc_b, coeffs);
        mix_kernel<<<512, 256, 73984, stream>>>(kernels, coeffs, wmix);
        conv_fb_kernel<<<512, 512, 0, stream>>>(x, wmix, out);
    }
}

// Round 13
// 98.689 us; speedup vs baseline: 1.4427x; 1.1737x over previous
//
#include <hip/hip_runtime.h>
#include <math.h>

typedef __attribute__((ext_vector_type(8))) short s16x8;
typedef __attribute__((ext_vector_type(4))) float f32x4;
typedef __attribute__((ext_vector_type(4))) unsigned int u32x4;

#define CCH 128
#define BSZ 32

// fp32 -> bf16 round-to-nearest-even (scalar)
static __device__ inline unsigned short f2bf(float f) {
    unsigned u = __float_as_uint(f);
    unsigned r = (u + 0x7FFFu + ((u >> 16) & 1u)) >> 16;
    return (unsigned short)r;
}

// packed f32x2 -> bf16x2 (RNE)
static __device__ inline unsigned cvtpk(float lo, float hi) {
    unsigned r;
    asm("v_cvt_pk_bf16_f32 %0, %1, %2" : "=v"(r) : "v"(lo), "v"(hi));
    return r;
}

// ================= BIG-WS PATH =================
// xws layout per (b,cc): [66 rows][72 cols][4 oct][8 bf16] = 304128 B.
//  storage row rs = gy+1 (rs 0/65 zero guards); storage col cp = gx+1
//  (cp 0, 65..71 zero); oct slot o' holds data oct o'^((cp>>1)&3).

// ---------------- prep: fused GAP + x->bf16 padded/swizzled relayout ----------
__global__ __launch_bounds__(256, 2) void prep_kernel(const float* __restrict__ x,
                                                      unsigned short* __restrict__ xws,
                                                      float* __restrict__ pooled2) {
    int bid = blockIdx.x;
    int b = bid >> 4, cc = (bid >> 2) & 3, q = bid & 3;
    int t = threadIdx.x;
    const float* xb = x + ((size_t)b * CCH + cc * 32) * 4096;
    unsigned short* xo = xws + (size_t)(b * 4 + cc) * (66 * 72 * 32);

    float sums[32];
#pragma unroll
    for (int c = 0; c < 32; ++c) sums[c] = 0.f;

#pragma unroll
    for (int it = 0; it < 2; ++it) {
        int task = t + it * 256;
        int gy = q * 16 + (task >> 5);
        int i = task & 31;
        int gx0 = 2 * i;
        float2 v2[32];
#pragma unroll
        for (int c = 0; c < 32; ++c) {
            v2[c] = *(const float2*)&xb[(size_t)c * 4096 + gy * 64 + gx0];
            sums[c] += v2[c].x + v2[c].y;
        }
        int rs = gy + 1;
        int cp0 = gx0 + 1, cp1 = gx0 + 2;
        int xor0 = (cp0 >> 1) & 3, xor1 = (cp1 >> 1) & 3;
        unsigned short* dp0 = xo + ((size_t)rs * 72 + cp0) * 32;
        unsigned short* dp1 = xo + ((size_t)rs * 72 + cp1) * 32;
#pragma unroll
        for (int od = 0; od < 4; ++od) {      // STATIC index into v2 (rule #20)
            u32x4 q0, q1;
#pragma unroll
            for (int j = 0; j < 4; ++j) {
                float2 a = v2[od * 8 + 2 * j];
                float2 c2 = v2[od * 8 + 2 * j + 1];
                q0[j] = cvtpk(a.x, c2.x);
                q1[j] = cvtpk(a.y, c2.y);
            }
            *(u32x4*)&dp0[(od ^ xor0) * 8] = q0;
            *(u32x4*)&dp1[(od ^ xor1) * 8] = q1;
        }
    }

    {
        int nz = 128 + ((q == 0 || q == 3) ? 72 : 0);
        if (t < nz) {
            int rs, cp;
            if (t < 128) {
                rs = q * 16 + 1 + (t >> 3);
                cp = ((t & 7) == 0) ? 0 : 64 + (t & 7);
            } else {
                rs = (q == 0) ? 0 : 65;
                cp = t - 128;
            }
            unsigned short* dp = xo + ((size_t)rs * 72 + cp) * 32;
            u32x4 zq = {0u, 0u, 0u, 0u};
#pragma unroll
            for (int o = 0; o < 4; ++o) *(u32x4*)&dp[o * 8] = zq;
        }
    }

    __shared__ float red[4][32];
    int l = t & 63, wv = t >> 6;
#pragma unroll
    for (int c = 0; c < 32; ++c) {
        float s = sums[c];
        s += __shfl_xor(s, 1, 64); s += __shfl_xor(s, 2, 64); s += __shfl_xor(s, 4, 64);
        s += __shfl_xor(s, 8, 64); s += __shfl_xor(s, 16, 64); s += __shfl_xor(s, 32, 64);
        if (l == 0) red[wv][c] = s;
    }
    __syncthreads();
    if (t < 32) {
        float tot = red[0][t] + red[1][t] + red[2][t] + red[3][t];
        pooled2[((size_t)(b * 4 + cc) * 4 + q) * 32 + t] = tot * (1.0f / 4096.0f);
    }
}

// ---------------- coeff2 ----------------
__global__ __launch_bounds__(128) void coeff2_kernel(const float* __restrict__ pooled2,
                                                     const float* __restrict__ fc_w,
                                                     const float* __restrict__ fc_b,
                                                     float* __restrict__ coeffs) {
    int t = threadIdx.x;
    int b = t >> 2, k = t & 3;
    float dot = fc_b[k];
#pragma unroll
    for (int cc = 0; cc < 4; ++cc) {
        const float4* p0 = (const float4*)(pooled2 + ((size_t)(b * 4 + cc) * 4 + 0) * 32);
        const float4* p1 = (const float4*)(pooled2 + ((size_t)(b * 4 + cc) * 4 + 1) * 32);
        const float4* p2 = (const float4*)(pooled2 + ((size_t)(b * 4 + cc) * 4 + 2) * 32);
        const float4* p3 = (const float4*)(pooled2 + ((size_t)(b * 4 + cc) * 4 + 3) * 32);
        const float4* w4 = (const float4*)(fc_w + k * CCH + cc * 32);
#pragma unroll
        for (int j = 0; j < 8; ++j) {
            float4 s4, w = w4[j];
            float4 a0 = p0[j], a1 = p1[j], a2 = p2[j], a3 = p3[j];
            s4.x = a0.x + a1.x + a2.x + a3.x; s4.y = a0.y + a1.y + a2.y + a3.y;
            s4.z = a0.z + a1.z + a2.z + a3.z; s4.w = a0.w + a1.w + a2.w + a3.w;
            dot += s4.x * w.x + s4.y * w.y + s4.z * w.z + s4.w * w.w;
        }
    }
    float s = 1.0f / (1.0f + expf(-dot));
    float m = s;
    m = fmaxf(m, __shfl_xor(m, 1, 64));
    m = fmaxf(m, __shfl_xor(m, 2, 64));
    float e = expf(s - m);
    float sum = e;
    sum += __shfl_xor(sum, 1, 64);
    sum += __shfl_xor(sum, 2, 64);
    coeffs[t] = e / sum;
}

// ---------------- mix (both paths) ----------------
__global__ __launch_bounds__(256) void mix_kernel(const float* __restrict__ kernels,
                                                  const float* __restrict__ coeffs,
                                                  unsigned short* __restrict__ wmix) {
    extern __shared__ float klds[];   // 73984 B
    int bid = blockIdx.x;
    int bq = bid & 15;
    int rest = bid >> 4;
    int cog = rest & 7, cc = rest >> 3;
    int t = threadIdx.x;

    const int KSTR = CCH * CCH * 9;
    for (int s = t; s < 4 * 16 * 288; s += 256) {
        int k = s / 4608;
        int rem = s - k * 4608;
        int co = rem / 288;
        int i = rem - co * 288;
        klds[k * 4624 + co * 289 + i] =
            kernels[(size_t)k * KSTR + ((size_t)(cog * 16 + co) * CCH + cc * 32) * 9 + i];
    }
    __syncthreads();

    int wr = cog >> 2, mt = cog & 3;
#pragma unroll
    for (int jb = 0; jb < 2; ++jb) {
        int b = bq + jb * 16;
        float cf0 = coeffs[b * 4 + 0];
        float cf1 = coeffs[b * 4 + 1];
        float cf2 = coeffs[b * 4 + 2];
        float cf3 = coeffs[b * 4 + 3];
        for (int s = t; s < 576; s += 256) {
            int lane = s & 63;
            int tj = s >> 6;
            int dy = tj / 3, dx = tj - dy * 3;
            int col = lane & 15;
            int ci8 = (lane >> 4) * 8;
            unsigned short vals[8];
#pragma unroll
            for (int e = 0; e < 8; ++e) {
                int idx = col * 289 + (ci8 + e) * 9 + dy * 3 + dx;
                float v = cf0 * klds[idx]
                        + cf1 * klds[4624 + idx]
                        + cf2 * klds[2 * 4624 + idx]
                        + cf3 * klds[3 * 4624 + idx];
                vals[e] = f2bf(v);
            }
            int p = cc * 3 + dy;
            size_t off = (size_t)b * 147456
                       + ((size_t)((p * 3 + dx) * 2 + wr) * 4 + mt) * 512 + (size_t)lane * 8;
            *(s16x8*)&wmix[off] = *(const s16x8*)vals;
        }
    }
}

// ---------------- conv (big path): register-slim DMA staging ----------------
// grid = 512 (32 b x 16 ytiles), 512 threads (8 waves: wr2 x wc4).
// Persistent VGPRs by construction: boff0..2 (3), vsoff (1), wtl pair (2),
// a[4] (16), transients; acc 64 AGPR. cc loop NOT unrolled.
__global__ __launch_bounds__(512, 4) void conv_kernel(const unsigned short* __restrict__ xws,
                                                      const unsigned short* __restrict__ wmix,
                                                      float* __restrict__ out) {
    __shared__ unsigned short xs[2][13824];   // 2 x 27648 B

    int bid = blockIdx.x;
    int b = bid & 31, ytile = bid >> 5;
    int y0 = ytile * 4;
    int t = threadIdx.x;
    int l = t & 63, w = t >> 6;
    int wr = w >> 2, wc = w & 3;
    int l15 = l & 15, g = l >> 4;

    // B-read lane constants: boff_dx = (l15+dx)*64 + (g^(((l15+dx)>>1)&3))*16
    // (swizzle term is nt- and row-independent because 8*nt % 4 == 0)
    int boff0 = (l15 + 0) * 64 + ((g ^ (((l15 + 0) >> 1) & 3)) * 16);
    int boff1 = (l15 + 1) * 64 + ((g ^ (((l15 + 1) >> 1) & 3)) * 16);
    int boff2 = (l15 + 2) * 64 + ((g ^ (((l15 + 2) >> 1) & 3)) * 16);
    int rowb = wc * 4608;                       // per-wave row byte base

    const char* wtl = (const char*)wmix + (size_t)b * 294912 + wr * 4096 + l * 16;
    const char* xsrc = (const char*)xws + ((size_t)(b * 4) * 66 + y0) * 4608;  // SGPR
    int vsoff = w * 1024 + l * 16;              // staging src/dst lane offset

#define STAGE(ccn, buf)                                                          \
    do {                                                                         \
        const char* srcb = xsrc + (size_t)(ccn) * 304128 + vsoff;                \
        char* dstb = (char*)&xs[0][0] + (buf) * 27648 + w * 1024;                \
        _Pragma("unroll")                                                        \
        for (int k = 0; k < 3; ++k)                                              \
            __builtin_amdgcn_global_load_lds(                                    \
                (const __attribute__((address_space(1))) void*)(srcb + k * 8192),\
                (__attribute__((address_space(3))) void*)(dstb + k * 8192),      \
                16, 0, 0);                                                       \
        if (w < 3)                                                               \
            __builtin_amdgcn_global_load_lds(                                    \
                (const __attribute__((address_space(1))) void*)(srcb + 24576),   \
                (__attribute__((address_space(3))) void*)(dstb + 24576),         \
                16, 0, 0);                                                       \
    } while (0)

    STAGE(0, 0);
    __syncthreads();

    f32x4 acc[4][4] = {};

#pragma unroll 1
    for (int cc = 0; cc < 4; ++cc) {
        if (cc < 3) STAGE(cc + 1, (cc + 1) & 1);   // full-phase latency cover
        const char* xb = (const char*)&xs[0][0] + (cc & 1) * 27648 + rowb;
        const char* wpc = wtl + (size_t)cc * 73728;
#pragma unroll
        for (int dy = 0; dy < 3; ++dy) {
#pragma unroll
            for (int dx = 0; dx < 3; ++dx) {
                const char* wp = wpc + (dy * 3 + dx) * 8192;
                s16x8 a[4];
#pragma unroll
                for (int mt = 0; mt < 4; ++mt)
                    a[mt] = *(const s16x8*)(wp + mt * 1024);
                int boffd = (dx == 0) ? boff0 : (dx == 1) ? boff1 : boff2;
                const char* xrow = xb + dy * 4608 + boffd;
#pragma unroll
                for (int nt = 0; nt < 4; ++nt) {
                    s16x8 bf = *(const s16x8*)(xrow + nt * 1024);
#pragma unroll
                    for (int mt = 0; mt < 4; ++mt)
                        acc[mt][nt] = __builtin_amdgcn_mfma_f32_16x16x32_bf16(
                            a[mt], bf, acc[mt][nt], 0, 0, 0);
                }
            }
        }
        __syncthreads();   // drains vmcnt (next buf staged) + lgkm (reads done)
    }
#undef STAGE

    int gy = y0 + wc;
#pragma unroll
    for (int mt = 0; mt < 4; ++mt)
#pragma unroll
        for (int nt = 0; nt < 4; ++nt) {
            int gxo = nt * 16 + l15;
#pragma unroll
            for (int j = 0; j < 4; ++j) {
                int co = wr * 64 + mt * 16 + g * 4 + j;
                out[(((size_t)b * CCH + co) * 64 + gy) * 64 + gxo] = acc[mt][nt][j];
            }
        }
}

// ================= FALLBACK PATH (round-6, proven) =================

__global__ __launch_bounds__(256) void pool_kernel(const float* __restrict__ x,
                                                   float* __restrict__ pooled) {
    int blk = blockIdx.x;
    const float4* x4 = (const float4*)(x + (size_t)blk * 4096);
    int t = threadIdx.x;
    float s = 0.f;
#pragma unroll
    for (int j = 0; j < 4; ++j) {
        float4 v = x4[j * 256 + t];
        s += v.x + v.y + v.z + v.w;
    }
#pragma unroll
    for (int off = 32; off; off >>= 1) s += __shfl_xor(s, off, 64);
    __shared__ float red[4];
    if ((t & 63) == 0) red[t >> 6] = s;
    __syncthreads();
    if (t == 0) {
        float tot = red[0] + red[1] + red[2] + red[3];
        pooled[blk] = tot * (1.0f / 4096.0f);
    }
}

__global__ __launch_bounds__(128) void coeff_kernel(const float* __restrict__ pooled,
                                                    const float* __restrict__ fc_w,
                                                    const float* __restrict__ fc_b,
                                                    float* __restrict__ coeffs) {
    int t = threadIdx.x;
    int b = t >> 2, k = t & 3;
    const float4* p4 = (const float4*)(pooled + b * CCH);
    const float4* w4 = (const float4*)(fc_w + k * CCH);
    float dot = fc_b[k];
#pragma unroll
    for (int j = 0; j < 32; ++j) {
        float4 a = p4[j], w = w4[j];
        dot += a.x * w.x + a.y * w.y + a.z * w.z + a.w * w.w;
    }
    float s = 1.0f / (1.0f + expf(-dot));
    float m = s;
    m = fmaxf(m, __shfl_xor(m, 1, 64));
    m = fmaxf(m, __shfl_xor(m, 2, 64));
    float e = expf(s - m);
    float sum = e;
    sum += __shfl_xor(sum, 1, 64);
    sum += __shfl_xor(sum, 2, 64);
    coeffs[t] = e / sum;
}

__global__ __launch_bounds__(512, 4) void conv_fb_kernel(const float* __restrict__ x,
                                                         const unsigned short* __restrict__ wmix,
                                                         float* __restrict__ out) {
    __shared__ unsigned short xsb[6 * 66 * 40];

    int bid = blockIdx.x;
    int b = bid & 31, ytile = bid >> 5;
    int y0 = ytile * 4;
    int t = threadIdx.x;
    int l = t & 63, w = t >> 6;
    int wr = w >> 2, wc = w & 3;
    int l15 = l & 15, g = l >> 4;

    const unsigned short* wb = wmix + (size_t)b * 147456;

    if (t < 240) {
        int row = t / 40;
        int colsel = (t / 20) & 1;
        int cpart = t % 20;
        *(unsigned*)&xsb[(row * 66 + colsel * 65) * 40 + cpart * 2] = 0u;
    }

    f32x4 acc[4][4] = {};

    for (int cc = 0; cc < 4; ++cc) {
        __syncthreads();
#pragma unroll
        for (int i = 0; i < 3; ++i) {
            int slot = w + i * 8;
            int row = slot >> 2, colhi = slot & 3;
            int gx = colhi * 16 + l15;
            int gy = y0 + row - 1;
            float v[8];
#pragma unroll
            for (int j = 0; j < 8; ++j) v[j] = 0.f;
            if ((unsigned)gy < 64u) {
                const float* xp = x + (((size_t)b * CCH + cc * 32 + g * 8) * 64 + gy) * 64 + gx;
#pragma unroll
                for (int j = 0; j < 8; ++j) v[j] = xp[(size_t)j * 4096];
            }
            unsigned pk[4];
#pragma unroll
            for (int j = 0; j < 4; ++j)
                pk[j] = (unsigned)f2bf(v[2 * j]) | ((unsigned)f2bf(v[2 * j + 1]) << 16);
            u32x4 qv; qv[0] = pk[0]; qv[1] = pk[1]; qv[2] = pk[2]; qv[3] = pk[3];
            *(u32x4*)&xsb[(size_t)(row * 66 + gx + 1) * 40 + g * 8] = qv;
        }
        __syncthreads();
#pragma unroll
        for (int dy = 0; dy < 3; ++dy) {
            int p = cc * 3 + dy;
            int xrow = wc + dy;
#pragma unroll
            for (int dx = 0; dx < 3; ++dx) {
                const unsigned short* wt = wb + ((size_t)((p * 3 + dx) * 2 + wr) * 4) * 512
                                              + (size_t)l * 8;
                s16x8 a[4];
#pragma unroll
                for (int mt = 0; mt < 4; ++mt)
                    a[mt] = *(const s16x8*)(wt + mt * 512);
#pragma unroll
                for (int nt = 0; nt < 4; ++nt) {
                    s16x8 bf = *(const s16x8*)&xsb[(size_t)(xrow * 66 + nt * 16 + l15 + dx) * 40 + g * 8];
#pragma unroll
                    for (int mt = 0; mt < 4; ++mt)
                        acc[mt][nt] = __builtin_amdgcn_mfma_f32_16x16x32_bf16(
                            a[mt], bf, acc[mt][nt], 0, 0, 0);
                }
            }
        }
    }

    int gy = y0 + wc;
#pragma unroll
    for (int mt = 0; mt < 4; ++mt)
#pragma unroll
        for (int nt = 0; nt < 4; ++nt) {
            int gxo = nt * 16 + l15;
#pragma unroll
            for (int j = 0; j < 4; ++j) {
                int co = wr * 64 + mt * 16 + g * 4 + j;
                out[(((size_t)b * CCH + co) * 64 + gy) * 64 + gxo] = acc[mt][nt][j];
            }
        }
}

extern "C" void kernel_launch(void* const* d_in, const int* in_sizes, int n_in,
                              void* d_out, int out_size, void* d_ws, size_t ws_size,
                              hipStream_t stream) {
    const float* x       = (const float*)d_in[0];   // [32,128,64,64]
    const float* kernels = (const float*)d_in[1];   // [4,128,128,3,3]
    const float* fc_w    = (const float*)d_in[2];   // [4,128]
    const float* fc_b    = (const float*)d_in[3];   // [4]
    float* out = (float*)d_out;

    hipFuncSetAttribute((const void*)mix_kernel,
                        hipFuncAttributeMaxDynamicSharedMemorySize, 73984);

    // pooled2 64KB @0 | coeffs @65536 | wmix @73728 (9.44MB) | xws @9510912 (38.93MB)
    const size_t NEED = 9510912ull + 38928384ull;   // 48.44 MB
    if (ws_size >= NEED) {
        float* pooled2        = (float*)d_ws;
        float* coeffs         = (float*)((char*)d_ws + 65536);
        unsigned short* wmix  = (unsigned short*)((char*)d_ws + 73728);
        unsigned short* xws   = (unsigned short*)((char*)d_ws + 9510912);

        prep_kernel<<<512, 256, 0, stream>>>(x, xws, pooled2);
        coeff2_kernel<<<1, 128, 0, stream>>>(pooled2, fc_w, fc_b, coeffs);
        mix_kernel<<<512, 256, 73984, stream>>>(kernels, coeffs, wmix);
        conv_kernel<<<512, 512, 0, stream>>>(xws, wmix, out);
    } else {
        float* pooled = (float*)d_ws;
        float* coeffs = pooled + BSZ * CCH;
        unsigned short* wmix = (unsigned short*)((char*)d_ws + 32768);

        pool_kernel<<<BSZ * CCH, 256, 0, stream>>>(x, pooled);
        coeff_kernel<<<1, 128, 0, stream>>>(pooled, fc_w, fc_b, coeffs);
        mix_kernel<<<512, 256, 73984, stream>>>(kernels, coeffs, wmix);
        conv_fb_kernel<<<512, 512, 0, stream>>>(x, wmix, out);
    }
}